// Round 1
// baseline (240.591 us; speedup 1.0000x reference)
//
#include <hip/hip_runtime.h>

typedef __attribute__((ext_vector_type(8))) short short8;
typedef __attribute__((ext_vector_type(4))) float f32x4;
typedef __attribute__((ext_vector_type(4))) unsigned short us4;

constexpr int NB = 8, NC = 256, IH = 64, IW = 96;
constexpr int PATCH = 21, RAD = 10;
constexpr int TI = 8, TJ = 8;           // pixel tile
constexpr int WIN = 28, NWIN = 784;     // x2 window per tile
constexpr int KC = 32, NKS = NC / KC;   // channel chunking
constexpr int LDK = 40;                 // padded LDS k-stride (shorts): 80B rows
constexpr int PLANE = IH * IW;          // 6144

__device__ __forceinline__ unsigned short f2bf(float f) {
  unsigned u = __builtin_bit_cast(unsigned, f);
  u += 0x7fffu + ((u >> 16) & 1u);      // RNE
  return (unsigned short)(u >> 16);
}

// out[b][pi][pj][i][j] = sum_c x1[b,c,i,j] * x2[b,c,i+pi-10,j+pj-10]  (0 if OOB)
// Band-GEMM: per (b, 8x8 pixel tile): G[64 x 784] = A^T B over K=256,
// A = x1 tile pixels, B = 28x28 zero-padded x2 window; out = band of G.
__global__ __launch_bounds__(512, 2) void corr_mfma(
    const float* __restrict__ x1, const float* __restrict__ x2,
    float* __restrict__ out) {
  __shared__ __attribute__((aligned(16))) unsigned short lsA[64 * LDK];
  __shared__ __attribute__((aligned(16))) unsigned short lsB[NWIN * LDK];

  const int t = threadIdx.x;
  const int b = blockIdx.y;
  const int ti = blockIdx.x / 12, tj = blockIdx.x % 12;
  const int i0 = ti * TI, j0 = tj * TJ;

  const int lane = t & 63;
  const int wv = t >> 6;        // wave 0..7
  const int mtp = wv >> 2;      // 0,1 -> M-tiles {2mtp, 2mtp+1}
  const int cg = wv & 3;        // col group
  const int cbeg = cg * 12;     // 13 col-tiles each; overlap at 12/24/36 (deduped at store)

  const int qk = lane >> 4;     // 0..3 (k quarter)
  const int lr = lane & 15;     // row/col within 16

  f32x4 acc[2][13];
#pragma unroll
  for (int a = 0; a < 2; ++a)
#pragma unroll
    for (int cc = 0; cc < 13; ++cc) acc[a][cc] = (f32x4){0.f, 0.f, 0.f, 0.f};

  // A staging assignment: thread -> (pixel m, k-quad)
  const int am = t & 63, ak4 = t >> 6;
  const int aii = am >> 3, ajj = am & 7;
  const float* x1p = x1 + ((size_t)b * NC + 4 * ak4) * PLANE
                        + (size_t)(i0 + aii) * IW + (j0 + ajj);
  const float* x2b = x2 + (size_t)b * NC * PLANE;

  for (int ks = 0; ks < NKS; ++ks) {
    __syncthreads();
    // ---- stage A: 64 px x 32 ch (each thread: 4 strided channel loads, pack b64)
    {
      const float* p = x1p + (size_t)ks * KC * PLANE;
      float f0 = p[0], f1 = p[PLANE], f2 = p[2 * PLANE], f3 = p[3 * PLANE];
      us4 v = {f2bf(f0), f2bf(f1), f2bf(f2), f2bf(f3)};
      *(us4*)&lsA[am * LDK + 4 * ak4] = v;
    }
    // ---- stage B: 784 window positions x 32 ch, zero OOB
    for (int w = t; w < NWIN; w += 512) {
      const int wi = w / WIN, wj = w - wi * WIN;
      const int gi = i0 - RAD + wi, gj = j0 - RAD + wj;
      const bool ok = ((unsigned)gi < (unsigned)IH) && ((unsigned)gj < (unsigned)IW);
      const float* p = x2b + ((size_t)(ks * KC) * IH + gi) * IW + gj;
      unsigned short* dst = &lsB[w * LDK];
#pragma unroll
      for (int k4 = 0; k4 < 8; ++k4) {
        const float* q = p + (size_t)(4 * k4) * PLANE;
        float f0 = ok ? q[0] : 0.f;
        float f1 = ok ? q[PLANE] : 0.f;
        float f2 = ok ? q[2 * PLANE] : 0.f;
        float f3 = ok ? q[3 * PLANE] : 0.f;
        us4 v = {f2bf(f0), f2bf(f1), f2bf(f2), f2bf(f3)};
        *(us4*)&dst[4 * k4] = v;
      }
    }
    __syncthreads();
    // ---- compute: wave = 2 M-tiles x 13 col-tiles
    short8 a0 = *(const short8*)&lsA[(32 * mtp + lr) * LDK + 8 * qk];
    short8 a1 = *(const short8*)&lsA[(32 * mtp + 16 + lr) * LDK + 8 * qk];
#pragma unroll
    for (int cc = 0; cc < 13; ++cc) {
      const int wrow = 16 * (cbeg + cc) + lr;
      short8 bf = *(const short8*)&lsB[wrow * LDK + 8 * qk];
      acc[0][cc] = __builtin_amdgcn_mfma_f32_16x16x32_bf16(a0, bf, acc[0][cc], 0, 0, 0);
      acc[1][cc] = __builtin_amdgcn_mfma_f32_16x16x32_bf16(a1, bf, acc[1][cc], 0, 0, 0);
    }
  }

  // ---- epilogue: extract band, scattered predicated stores
#pragma unroll
  for (int a = 0; a < 2; ++a) {
    const int mb = 16 * (2 * mtp + a) + qk * 4;   // C/D row = (lane>>4)*4 + reg (m89)
#pragma unroll
    for (int cc = 0; cc < 13; ++cc) {
      if (cg > 0 && cc == 0) continue;            // dedup overlapped col-tile
      const int n = 16 * (cbeg + cc) + lr;        // C/D col = lane&15
      const int wi = n / WIN, wj = n - wi * WIN;
#pragma unroll
      for (int r = 0; r < 4; ++r) {
        const int m = mb + r;
        const int ii = m >> 3, jj = m & 7;
        const int pi = wi - ii, pj = wj - jj;
        if ((unsigned)pi < (unsigned)PATCH && (unsigned)pj < (unsigned)PATCH) {
          out[((((size_t)b * PATCH + pi) * PATCH + pj) * IH + (i0 + ii)) * IW + (j0 + jj)] =
              acc[a][cc][r];
        }
      }
    }
  }
}

extern "C" void kernel_launch(void* const* d_in, const int* in_sizes, int n_in,
                              void* d_out, int out_size, void* d_ws, size_t ws_size,
                              hipStream_t stream) {
  const float* x1 = (const float*)d_in[0];
  const float* x2 = (const float*)d_in[1];
  float* out = (float*)d_out;
  dim3 grid(96, NB);   // 12x8 pixel tiles x 8 batches
  corr_mfma<<<grid, 512, 0, stream>>>(x1, x2, out);
}

// Round 2
// 140.293 us; speedup vs baseline: 1.7149x; 1.7149x over previous
//
#include <hip/hip_runtime.h>

typedef __attribute__((ext_vector_type(8))) short short8;
typedef __attribute__((ext_vector_type(4))) float f32x4;
typedef __attribute__((ext_vector_type(4))) unsigned short us4;

constexpr int NB = 8, NC = 256, IH = 64, IW = 96;
constexpr int PATCH = 21, RAD = 10;
constexpr int TI = 8, TJ = 8;           // pixel tile
constexpr int WIN = 28, NWIN = 784;     // x2 window per tile
constexpr int KC = 32, NKS = NC / KC;   // channel chunking
constexpr int LDB = 40;                 // lsB row stride (shorts) = 80B: 16B-aligned, 2-way-free reads
constexpr int PLANE = IH * IW;          // 6144
constexpr size_t TSZ = (size_t)NB * IH * IW * NC;  // elements per tensor

__device__ __forceinline__ unsigned short f2bf(float f) {
  unsigned u = __builtin_bit_cast(unsigned, f);
  u += 0x7fffu + ((u >> 16) & 1u);      // RNE
  return (unsigned short)(u >> 16);
}

// ---------------- pre-pass: NCHW fp32 -> NHWC bf16 ----------------
__global__ __launch_bounds__(256) void to_nhwc_bf16(const float* __restrict__ src,
                                                    unsigned short* __restrict__ dst) {
  __shared__ float ls[32 * 97];
  const int blk = blockIdx.x;                 // b*512 + i*8 + ct
  const int ct = blk & 7, i = (blk >> 3) & 63, b = blk >> 9;
  const int c0 = ct * 32;
  const int t = threadIdx.x;
  const float* sp = src + ((size_t)b * NC + c0) * PLANE + (size_t)i * IW;
#pragma unroll
  for (int k = 0; k < 12; ++k) {              // read 32c x 96j, coalesced along j
    int idx = k * 256 + t;
    int c = idx / 96, j = idx - c * 96;
    ls[c * 97 + j] = sp[(size_t)c * PLANE + j];
  }
  __syncthreads();
  unsigned short* dp = dst + (((size_t)b * IH + i) * IW) * NC + c0;
#pragma unroll
  for (int k = 0; k < 3; ++k) {               // write 96j x 8 chunks of 4ch (8B)
    int o = k * 256 + t;
    int j = o >> 3, cq = o & 7;
    us4 v = {f2bf(ls[(cq * 4 + 0) * 97 + j]), f2bf(ls[(cq * 4 + 1) * 97 + j]),
             f2bf(ls[(cq * 4 + 2) * 97 + j]), f2bf(ls[(cq * 4 + 3) * 97 + j])};
    *(us4*)&dp[(size_t)j * NC + cq * 4] = v;
  }
}

// ---------------- main: band-GEMM on NHWC bf16 ----------------
// out[b][pi][pj][i][j] = sum_c x1[b,c,i,j]*x2[b,c,i+pi-10,j+pj-10]
__global__ __launch_bounds__(512, 2) void corr_main(
    const unsigned short* __restrict__ x1t, const unsigned short* __restrict__ x2t,
    float* __restrict__ out) {
  __shared__ __attribute__((aligned(16))) unsigned short lsB[NWIN * LDB];  // 62720 B

  const int t = threadIdx.x;
  const int bid = blockIdx.x;
  const int b = bid & 7;                      // XCD-locality: batch b -> XCD b
  const int tile = bid >> 3;
  const int ti = tile / 12, tj = tile - ti * 12;
  const int i0 = ti * TI, j0 = tj * TJ;

  const int lane = t & 63;
  const int wv = t >> 6;
  const int mtp = wv >> 2;                    // M-tiles {2mtp, 2mtp+1}
  const int cg = wv & 3;
  const int cbeg = cg * 12;                   // 13 col-tiles, overlap deduped at store

  const int qk = lane >> 4;                   // k quarter
  const int lr = lane & 15;

  f32x4 acc[2][13];
#pragma unroll
  for (int a = 0; a < 2; ++a)
#pragma unroll
    for (int cc = 0; cc < 13; ++cc) acc[a][cc] = (f32x4){0.f, 0.f, 0.f, 0.f};

  // per-lane A fragment pointers (direct global, no LDS)
  const int m0 = 32 * mtp + lr, m1 = m0 + 16;
  const unsigned short* a0p =
      x1t + (((size_t)b * IH + i0 + (m0 >> 3)) * IW + j0 + (m0 & 7)) * NC + qk * 8;
  const unsigned short* a1p =
      x1t + (((size_t)b * IH + i0 + (m1 >> 3)) * IW + j0 + (m1 & 7)) * NC + qk * 8;
  const unsigned short* x2b = x2t + (size_t)b * PLANE * NC;

  for (int ks = 0; ks < NKS; ++ks) {
    // A-fragment loads issued before barriers -> latency hides under staging
    short8 a0 = *(const short8*)(a0p + ks * KC);
    short8 a1 = *(const short8*)(a1p + ks * KC);
    __syncthreads();
    // stage B: 784 positions x 32ch, 16B chunks, zero OOB
#pragma unroll
    for (int it = 0; it < 7; ++it) {
      int q = t + it * 512;
      if (q < NWIN * 4) {
        int w = q >> 2, c4 = q & 3;
        int wi = w / WIN, wj = w - wi * WIN;
        int gi = i0 - RAD + wi, gj = j0 - RAD + wj;
        short8 v = {0, 0, 0, 0, 0, 0, 0, 0};
        if (((unsigned)gi < (unsigned)IH) && ((unsigned)gj < (unsigned)IW))
          v = *(const short8*)(x2b + ((size_t)(gi * IW + gj)) * NC + ks * KC + c4 * 8);
        *(short8*)&lsB[w * LDB + c4 * 8] = v;
      }
    }
    __syncthreads();
#pragma unroll
    for (int cc = 0; cc < 13; ++cc) {
      int wrow = 16 * (cbeg + cc) + lr;
      short8 bf = *(const short8*)&lsB[wrow * LDB + qk * 8];
      acc[0][cc] = __builtin_amdgcn_mfma_f32_16x16x32_bf16(a0, bf, acc[0][cc], 0, 0, 0);
      acc[1][cc] = __builtin_amdgcn_mfma_f32_16x16x32_bf16(a1, bf, acc[1][cc], 0, 0, 0);
    }
  }

  // epilogue: extract band, predicated scattered stores (validated in R1)
#pragma unroll
  for (int a = 0; a < 2; ++a) {
    const int mb = 16 * (2 * mtp + a) + qk * 4;
#pragma unroll
    for (int cc = 0; cc < 13; ++cc) {
      if (cg > 0 && cc == 0) continue;
      const int n = 16 * (cbeg + cc) + lr;
      const int wi = n / WIN, wj = n - wi * WIN;
#pragma unroll
      for (int r = 0; r < 4; ++r) {
        const int m = mb + r;
        const int ii = m >> 3, jj = m & 7;
        const int pi = wi - ii, pj = wj - jj;
        if ((unsigned)pi < (unsigned)PATCH && (unsigned)pj < (unsigned)PATCH) {
          out[((((size_t)b * PATCH + pi) * PATCH + pj) * IH + (i0 + ii)) * IW + (j0 + jj)] =
              acc[a][cc][r];
        }
      }
    }
  }
}

// ---------------- fallback (R1, validated): NCHW fp32 in-kernel ----------------
constexpr int LDKF = 40;
__global__ __launch_bounds__(512, 2) void corr_mfma_fb(
    const float* __restrict__ x1, const float* __restrict__ x2, float* __restrict__ out) {
  __shared__ __attribute__((aligned(16))) unsigned short lsA[64 * LDKF];
  __shared__ __attribute__((aligned(16))) unsigned short lsB[NWIN * LDKF];
  const int t = threadIdx.x;
  const int b = blockIdx.y;
  const int ti = blockIdx.x / 12, tj = blockIdx.x % 12;
  const int i0 = ti * TI, j0 = tj * TJ;
  const int lane = t & 63, wv = t >> 6;
  const int mtp = wv >> 2, cg = wv & 3, cbeg = cg * 12;
  const int qk = lane >> 4, lr = lane & 15;
  f32x4 acc[2][13];
#pragma unroll
  for (int a = 0; a < 2; ++a)
#pragma unroll
    for (int cc = 0; cc < 13; ++cc) acc[a][cc] = (f32x4){0.f, 0.f, 0.f, 0.f};
  const int am = t & 63, ak4 = t >> 6;
  const int aii = am >> 3, ajj = am & 7;
  const float* x1p = x1 + ((size_t)b * NC + 4 * ak4) * PLANE + (size_t)(i0 + aii) * IW + (j0 + ajj);
  const float* x2b = x2 + (size_t)b * NC * PLANE;
  for (int ks = 0; ks < NKS; ++ks) {
    __syncthreads();
    {
      const float* p = x1p + (size_t)ks * KC * PLANE;
      us4 v = {f2bf(p[0]), f2bf(p[PLANE]), f2bf(p[2 * PLANE]), f2bf(p[3 * PLANE])};
      *(us4*)&lsA[am * LDKF + 4 * ak4] = v;
    }
    for (int w = t; w < NWIN; w += 512) {
      const int wi = w / WIN, wj = w - wi * WIN;
      const int gi = i0 - RAD + wi, gj = j0 - RAD + wj;
      const bool ok = ((unsigned)gi < (unsigned)IH) && ((unsigned)gj < (unsigned)IW);
      const float* p = x2b + ((size_t)(ks * KC) * IH + gi) * IW + gj;
      unsigned short* dst = &lsB[w * LDKF];
#pragma unroll
      for (int k4 = 0; k4 < 8; ++k4) {
        const float* q = p + (size_t)(4 * k4) * PLANE;
        us4 v = {f2bf(ok ? q[0] : 0.f), f2bf(ok ? q[PLANE] : 0.f),
                 f2bf(ok ? q[2 * PLANE] : 0.f), f2bf(ok ? q[3 * PLANE] : 0.f)};
        *(us4*)&dst[4 * k4] = v;
      }
    }
    __syncthreads();
    short8 a0 = *(const short8*)&lsA[(32 * mtp + lr) * LDKF + 8 * qk];
    short8 a1 = *(const short8*)&lsA[(32 * mtp + 16 + lr) * LDKF + 8 * qk];
#pragma unroll
    for (int cc = 0; cc < 13; ++cc) {
      const int wrow = 16 * (cbeg + cc) + lr;
      short8 bf = *(const short8*)&lsB[wrow * LDKF + 8 * qk];
      acc[0][cc] = __builtin_amdgcn_mfma_f32_16x16x32_bf16(a0, bf, acc[0][cc], 0, 0, 0);
      acc[1][cc] = __builtin_amdgcn_mfma_f32_16x16x32_bf16(a1, bf, acc[1][cc], 0, 0, 0);
    }
  }
#pragma unroll
  for (int a = 0; a < 2; ++a) {
    const int mb = 16 * (2 * mtp + a) + qk * 4;
#pragma unroll
    for (int cc = 0; cc < 13; ++cc) {
      if (cg > 0 && cc == 0) continue;
      const int n = 16 * (cbeg + cc) + lr;
      const int wi = n / WIN, wj = n - wi * WIN;
#pragma unroll
      for (int r = 0; r < 4; ++r) {
        const int m = mb + r;
        const int ii = m >> 3, jj = m & 7;
        const int pi = wi - ii, pj = wj - jj;
        if ((unsigned)pi < (unsigned)PATCH && (unsigned)pj < (unsigned)PATCH)
          out[((((size_t)b * PATCH + pi) * PATCH + pj) * IH + (i0 + ii)) * IW + (j0 + jj)] =
              acc[a][cc][r];
      }
    }
  }
}

extern "C" void kernel_launch(void* const* d_in, const int* in_sizes, int n_in,
                              void* d_out, int out_size, void* d_ws, size_t ws_size,
                              hipStream_t stream) {
  const float* x1 = (const float*)d_in[0];
  const float* x2 = (const float*)d_in[1];
  float* out = (float*)d_out;
  const size_t need = 2 * TSZ * sizeof(unsigned short);   // 50.3 MB
  if (ws_size >= need) {
    unsigned short* x1t = (unsigned short*)d_ws;
    unsigned short* x2t = x1t + TSZ;
    to_nhwc_bf16<<<NB * IH * 8, 256, 0, stream>>>(x1, x1t);
    to_nhwc_bf16<<<NB * IH * 8, 256, 0, stream>>>(x2, x2t);
    corr_main<<<NB * 96, 512, 0, stream>>>(x1t, x2t, out);
  } else {
    dim3 grid(96, NB);
    corr_mfma_fb<<<grid, 512, 0, stream>>>(x1, x2, out);
  }
}